// Round 14
// baseline (374.176 us; speedup 1.0000x reference)
//
#include <hip/hip_runtime.h>
#include <hip/hip_bf16.h>

// ModulatedConv2d b=16, ic=oc=512, k=3, h=w=64.
// R14: 4 waves x 128x128 wave-tile (acc[8][8]=256 AGPR), 1 wave/SIMD
// (launch_bounds(256,1) -> 512 unified regs). Full one-step register
// double-buffer of fragments (fA/fB[2][8], 128 VGPR) => MFMA never waits on
// LDS; LDS frag traffic 96->64 KB/step (squarer tile). Ring-4 LDS (128KB),
// 8 GLL/thread/step, VMW(8)+BAR per step (audited ledger), involution
// swizzle (0 conflicts), linear A offsets, per-tap hoisted B pointers.

typedef __bf16 bf16x8 __attribute__((ext_vector_type(8)));
typedef float  f32x4  __attribute__((ext_vector_type(4)));

#define IC   512
#define OC   512
#define HW   4096
#define KTOT 4608

typedef __attribute__((address_space(3))) unsigned lds_u32;
typedef const __attribute__((address_space(1))) unsigned glb_u32;
#define GLL16(gsrc, ldst) \
    __builtin_amdgcn_global_load_lds((glb_u32*)(gsrc), (lds_u32*)(ldst), 16, 0, 0)
#define BAR()   asm volatile("s_barrier" ::: "memory")

template<int N> __device__ __forceinline__ void vmw() {
    asm volatile("s_waitcnt vmcnt(%0)" :: "n"(N) : "memory");
}

#define MFMA1(A, B, C) __builtin_amdgcn_mfma_f32_16x16x32_bf16(A, B, C, 0, 0, 0)

// ---------------- kernel 1: style modulation s[b][i] ----------------
__global__ __launch_bounds__(256) void style_mod_kernel(
    const float* __restrict__ style, const float* __restrict__ mod_w,
    const float* __restrict__ mod_b, float* __restrict__ s_out)
{
    int pair = blockIdx.x * 4 + (threadIdx.x >> 6);
    int lane = threadIdx.x & 63;
    int b = pair >> 9;
    int i = pair & 511;
    const float4* sv = (const float4*)(style + b * 512);
    const float4* wv = (const float4*)(mod_w + i * 512);
    float4 a0 = sv[lane * 2], a1 = sv[lane * 2 + 1];
    float4 w0 = wv[lane * 2], w1 = wv[lane * 2 + 1];
    float sum = a0.x*w0.x + a0.y*w0.y + a0.z*w0.z + a0.w*w0.w
              + a1.x*w1.x + a1.y*w1.y + a1.z*w1.z + a1.w*w1.w;
    #pragma unroll
    for (int off = 32; off; off >>= 1) sum += __shfl_xor(sum, off);
    if (lane == 0) s_out[pair] = sum + mod_b[i];
}

// ------------- kernel 2: demod + bf16 wmod, block per oc -------------
__global__ __launch_bounds__(256) void wmod_kernel(
    const float* __restrict__ weight,   // [512][4608] (e = ic*9+tap)
    const float* __restrict__ s_in,     // [16][512]
    __hip_bfloat16* __restrict__ wmod)  // [16*512][4608] (e' = tap*512+ic)
{
    int oc = blockIdx.x;
    __shared__ float w_sh[4608];
    __shared__ float s_sh[8192];
    __shared__ float q_sh[512];
    __shared__ float demod_sh[16];
    int t = threadIdx.x;
    const float* wrow = weight + (size_t)oc * KTOT;
    for (int e = t; e < 4608; e += 256) w_sh[e] = wrow[e];
    for (int e = t; e < 8192; e += 256) s_sh[e] = s_in[e];
    __syncthreads();
    for (int ic = t; ic < 512; ic += 256) {
        float q = 0.f;
        #pragma unroll
        for (int tap = 0; tap < 9; ++tap) { float w = w_sh[ic * 9 + tap]; q += w * w; }
        q_sh[ic] = q;
    }
    __syncthreads();
    int bb = t >> 4, li = t & 15;
    float part = 0.f;
    for (int ic = li; ic < 512; ic += 16) {
        float sv = s_sh[bb * 512 + ic];
        part += q_sh[ic] * sv * sv;
    }
    #pragma unroll
    for (int off = 8; off; off >>= 1) part += __shfl_xor(part, off, 16);
    if (li == 0) demod_sh[bb] = rsqrtf(part + 1e-8f);
    __syncthreads();
    for (int b2 = 0; b2 < 16; ++b2) {
        float dm = demod_sh[b2];
        const float* srow = s_sh + b2 * 512;
        __hip_bfloat16* dst = wmod + ((size_t)b2 * 512 + oc) * KTOT;
        for (int ep = t; ep < 4608; ep += 256) {
            int tap = ep >> 9, ic = ep & 511;
            dst[ep] = __float2bfloat16(w_sh[ic * 9 + tap] * srow[ic] * dm);
        }
    }
}

// ------------- kernel 3a: zero pad row of xT -------------
__global__ void zero_row_kernel(__hip_bfloat16* xT) {
    ((unsigned*)(xT + ((size_t)blockIdx.x * 4097 + 4096) * 512))[threadIdx.x] = 0u;
}

// ------------- kernel 3b: x [b][ic][pix] f32 -> xT [b][pix][ic] bf16 -------------
__global__ __launch_bounds__(256) void xpose_kernel(
    const float* __restrict__ x, __hip_bfloat16* __restrict__ xT)
{
    __shared__ __align__(16) float tile[64][68];
    int b = blockIdx.z, ic0 = blockIdx.y * 64, p0 = blockIdx.x * 64;
    int t = threadIdx.x;
    const float* xb = x + ((size_t)b * 512 + ic0) * 4096 + p0;
    int rr = t >> 4, cc = (t & 15) * 4;
    #pragma unroll
    for (int i = 0; i < 4; ++i) {
        float4 v = *(const float4*)(xb + (size_t)(rr + i * 16) * 4096 + cc);
        *(float4*)&tile[rr + i * 16][cc] = v;
    }
    __syncthreads();
    int pr = t >> 2, io = (t & 3) * 16;
    __hip_bfloat16 obuf[16];
    #pragma unroll
    for (int j = 0; j < 16; ++j) obuf[j] = __float2bfloat16(tile[io + j][pr]);
    __hip_bfloat16* dst = xT + ((size_t)b * 4097 + p0 + pr) * 512 + ic0 + io;
    *(uint4*)dst       = *(uint4*)&obuf[0];
    *(uint4*)(dst + 8) = *(uint4*)&obuf[8];
}

// ------------- kernel 4: conv, 4x(128x128) waves, 1 wave/SIMD, ring-4 -------------
__global__ __launch_bounds__(256, 1) void conv_kernel(
    const __hip_bfloat16* __restrict__ xT,    // [16][4097][512]
    const __hip_bfloat16* __restrict__ wmod,  // [16*512][4608]
    const float* __restrict__ bias,
    float* __restrict__ out)                  // [16][512][4096]
{
    __shared__ __align__(16) __hip_bfloat16 Ash[4][256 * 32];   // 64 KB
    __shared__ __align__(16) __hip_bfloat16 Bsh[4][256 * 32];   // 64 KB

    const int t    = threadIdx.x;
    const int lane = t & 63;
    const int wid  = t >> 6;      // 0..3
    const int wm   = wid >> 1;    // 0..1 (M half: 128 oc rows)
    const int wn   = wid & 1;     // 0..1 (N half: 128 px)
    const int lr   = lane & 15;
    const int lq   = lane >> 4;

    // block decode: 512 blocks; per XCD 2 b's; oc-tile inner (B-panel L2 reuse)
    int bid = blockIdx.x;
    int xcd = bid & 7, idx = bid >> 3;
    int oc1 = idx & 1;
    int nt  = (idx >> 1) & 15;
    int bb  = (idx >> 5) & 1;
    int b   = xcd * 2 + bb;
    int oc0 = oc1 * 256, n0 = nt * 256;

    const __hip_bfloat16* wb = wmod + (size_t)(b * 512 + oc0) * KTOT;
    const __hip_bfloat16* xb = xT + (size_t)b * 4097 * 512;

    // stage geometry: tile [256 rows][32 k]; 16B unit u: row u>>2, phys quad
    // u&3. Thread t owns units t+256j (rows (t>>2)+64j, quad t&3 invariant).
    // involution swizzle (verified 0 conflicts): logical quad = phys ^ ((row>>1)&3).
    const int qoff = (((t & 3) ^ ((t >> 3) & 3)) * 8);
    const int srow = t >> 2;                 // 0..63
    const int p0g  = n0 + srow;
    const int y0p  = p0g >> 6, x0p = p0g & 63;

    const __hip_bfloat16* pA0 = wb + (size_t)srow * KTOT + qoff;
    const __hip_bfloat16* pA1 = pA0 + (size_t)64  * KTOT;
    const __hip_bfloat16* pA2 = pA0 + (size_t)128 * KTOT;
    const __hip_bfloat16* pA3 = pA0 + (size_t)192 * KTOT;

    // fragment-read bases with matching swizzle
    const int swq = (lq ^ ((lr >> 1) & 3)) * 8;
    const int arb = (wm * 128 + lr) * 32 + swq;
    const int brb = (wn * 128 + lr) * 32 + swq;

    f32x4 acc[8][8] = {};                 // 256 AGPR
    bf16x8 fA[2][8], fB[2][8];            // 128 VGPR ping-pong

    // per-tap B stage pointers, px rows srow+{0,64,128,192} (+{0..3} img rows)
    const __hip_bfloat16 *pB0, *pB1, *pB2, *pB3, *nB0, *nB1, *nB2, *nB3;
    auto bptrs = [&](int tap, const __hip_bfloat16*& P0, const __hip_bfloat16*& P1,
                     const __hip_bfloat16*& P2, const __hip_bfloat16*& P3) {
        int dy = tap / 3 - 1, dx = tap % 3 - 1;
        int sx = x0p + dx;
        bool okx = ((unsigned)sx < 64u);
        int sy0 = y0p + dy;
        int q0 = (okx & ((unsigned)(sy0    ) < 64u)) ? ((sy0    ) * 64 + sx) : 4096;
        int q1 = (okx & ((unsigned)(sy0 + 1) < 64u)) ? ((sy0 + 1) * 64 + sx) : 4096;
        int q2 = (okx & ((unsigned)(sy0 + 2) < 64u)) ? ((sy0 + 2) * 64 + sx) : 4096;
        int q3 = (okx & ((unsigned)(sy0 + 3) < 64u)) ? ((sy0 + 3) * 64 + sx) : 4096;
        P0 = xb + (size_t)q0 * 512 + qoff;
        P1 = xb + (size_t)q1 * 512 + qoff;
        P2 = xb + (size_t)q2 * 512 + qoff;
        P3 = xb + (size_t)q3 * 512 + qoff;
    };

#define STAGE_A(SB, OFF) { \
    GLL16(pA0 + (OFF), &Ash[SB][t * 8]); \
    GLL16(pA1 + (OFF), &Ash[SB][(t + 256) * 8]); \
    GLL16(pA2 + (OFF), &Ash[SB][(t + 512) * 8]); \
    GLL16(pA3 + (OFF), &Ash[SB][(t + 768) * 8]); }
#define STAGE_B(SB, Q0, Q1, Q2, Q3, OFF) { \
    GLL16((Q0) + (OFF), &Bsh[SB][t * 8]); \
    GLL16((Q1) + (OFF), &Bsh[SB][(t + 256) * 8]); \
    GLL16((Q2) + (OFF), &Bsh[SB][(t + 512) * 8]); \
    GLL16((Q3) + (OFF), &Bsh[SB][(t + 768) * 8]); }

// prefetch frags of tile SL into parity P (16 ds_read_b128)
#define PF(P, SL) { \
    _Pragma("unroll") for (int mi = 0; mi < 8; ++mi) \
        fA[P][mi] = *(const bf16x8*)(&Ash[SL][arb + mi * 512]); \
    _Pragma("unroll") for (int ni = 0; ni < 8; ++ni) \
        fB[P][ni] = *(const bf16x8*)(&Bsh[SL][brb + ni * 512]); }

// 64 MFMA on parity P
#define MM(P) { \
    __builtin_amdgcn_s_setprio(1); \
    _Pragma("unroll") for (int mi = 0; mi < 8; ++mi) \
        _Pragma("unroll") for (int ni = 0; ni < 8; ++ni) \
            acc[mi][ni] = MFMA1(fA[P][mi], fB[P][ni], acc[mi][ni]); \
    __builtin_amdgcn_s_setprio(0); }

// step j (=tap*16+CH): stage tile j+3 (slot (j+3)&3), prefetch frags(j+1)
// from slot (j+1)&3 [resident: VMW(8)@end of j-1 drained tile j+1], 64 MFMA
// on frags(j) [parity j&1], VMW(8), BAR.
#define STEP(CH, DO_STAGE, BNXT) { \
    const int sl = ((CH) + 1) & 3, ss = ((CH) + 3) & 3; \
    const int cp = (CH) & 1, np = ((CH) + 1) & 1; \
    if (DO_STAGE) { \
        STAGE_A(ss, ((CH) + 3) * 32); \
        if ((CH) < 13) { STAGE_B(ss, pB0, pB1, pB2, pB3, ((CH) + 3) * 32); } \
        else           { STAGE_B(ss, BNXT##0, BNXT##1, BNXT##2, BNXT##3, ((CH) - 13) * 32); } \
    } \
    PF(np, sl); \
    MM(cp); \
    vmw<8>(); \
    BAR(); }

    bptrs(0, pB0, pB1, pB2, pB3);

    // prologue: stage tiles 0,1,2 (slots 0,1,2); VMW(16) -> tile 0 resident;
    // prefetch frags(0) into parity 0.
    STAGE_A(0, 0);  STAGE_B(0, pB0, pB1, pB2, pB3, 0);
    STAGE_A(1, 32); STAGE_B(1, pB0, pB1, pB2, pB3, 32);
    STAGE_A(2, 64); STAGE_B(2, pB0, pB1, pB2, pB3, 64);
    vmw<16>();
    BAR();
    PF(0, 0);

    // taps 0..7: 16 full steps each
    for (int tap = 0; tap < 8; ++tap) {
        bptrs(tap + 1, nB0, nB1, nB2, nB3);
        #pragma unroll
        for (int ch = 0; ch < 16; ++ch) {
            STEP(ch, true, nB);
        }
        pA0 += 512; pA1 += 512; pA2 += 512; pA3 += 512;
        pB0 = nB0; pB1 = nB1; pB2 = nB2; pB3 = nB3;
    }

    // tap 8 (peeled): stage while j+3 <= 143 (ch <= 12)
    #pragma unroll
    for (int ch = 0; ch < 13; ++ch) {
        STEP(ch, true, nB);
    }
    // ch 13 (j=141): no stage; PF(142) [resident]; MM(141); drain tile 143
    { PF(0, 2); MM(1); vmw<0>(); BAR(); }
    // ch 14 (j=142): PF(143); MM(142)
    { PF(1, 3); MM(0); }
    // ch 15 (j=143): final MFMA
    MM(1);
#undef STEP
#undef PF
#undef MM
#undef STAGE_A
#undef STAGE_B

    // ---- epilogue ----
    #pragma unroll
    for (int mi = 0; mi < 8; ++mi) {
        int oc = oc0 + wm * 128 + mi * 16 + lq * 4;
        #pragma unroll
        for (int ni = 0; ni < 8; ++ni) {
            int n = n0 + wn * 128 + ni * 16 + lr;
            #pragma unroll
            for (int v = 0; v < 4; ++v) {
                float r = acc[mi][ni][v] + bias[oc + v];
                out[((size_t)(b * OC + oc + v)) * HW + n] = r;
            }
        }
    }
}

extern "C" void kernel_launch(void* const* d_in, const int* in_sizes, int n_in,
                              void* d_out, int out_size, void* d_ws, size_t ws_size,
                              hipStream_t stream) {
    const float* x      = (const float*)d_in[0];
    const float* style  = (const float*)d_in[1];
    const float* weight = (const float*)d_in[2];
    const float* bias   = (const float*)d_in[3];
    const float* mod_w  = (const float*)d_in[4];
    const float* mod_b  = (const float*)d_in[5];
    float* out = (float*)d_out;

    // ws: s [32KB] | wmod bf16 [75.5MB] | xT bf16 [67.2MB]
    float* s_ws = (float*)d_ws;
    __hip_bfloat16* wmod = (__hip_bfloat16*)((char*)d_ws + 32768);
    __hip_bfloat16* xT   = (__hip_bfloat16*)((char*)d_ws + 32768 + (size_t)16 * 512 * KTOT * 2);

    style_mod_kernel<<<2048, 256, 0, stream>>>(style, mod_w, mod_b, s_ws);
    wmod_kernel<<<512, 256, 0, stream>>>(weight, s_ws, wmod);
    zero_row_kernel<<<16, 256, 0, stream>>>(xT);
    dim3 tgrid(64, 8, 16);
    xpose_kernel<<<tgrid, 256, 0, stream>>>(x, xT);
    conv_kernel<<<512, 256, 0, stream>>>(xT, wmod, bias, out);
}

// Round 15
// 328.775 us; speedup vs baseline: 1.1381x; 1.1381x over previous
//
#include <hip/hip_runtime.h>
#include <hip/hip_bf16.h>

// ModulatedConv2d b=16, ic=oc=512, k=3, h=w=64.
// R15: faithful m201 8-phase port. 256x256, BK=64, dbuf-2 (128KB), 8 waves.
// KEY FIX vs R12: each phase ds-reads ONLY the 4-8 b128 its 16-MFMA cluster
// consumes (peak 32 live frag VGPRs, no spill), per m201 template.
// Phase stages (WAR-audited): ph1 A(2i+1)->buf1, ph4 Bh0(buf0), ph5 Bh1+Ah0,
// ph6 Ah1(buf0), ph8 B(2i+3)->buf1. vmw<2>@ph4, vmw<4>@ph8 (flight ledger).

typedef __bf16 bf16x8 __attribute__((ext_vector_type(8)));
typedef float  f32x4  __attribute__((ext_vector_type(4)));

#define IC   512
#define OC   512
#define HW   4096
#define KTOT 4608

typedef __attribute__((address_space(3))) unsigned lds_u32;
typedef const __attribute__((address_space(1))) unsigned glb_u32;
#define GLL16(gsrc, ldst) \
    __builtin_amdgcn_global_load_lds((glb_u32*)(gsrc), (lds_u32*)(ldst), 16, 0, 0)
#define BAR()   asm volatile("s_barrier" ::: "memory")
#define LGKM0() asm volatile("s_waitcnt lgkmcnt(0)" ::: "memory")

template<int N> __device__ __forceinline__ void vmw() {
    asm volatile("s_waitcnt vmcnt(%0)" :: "n"(N) : "memory");
}

#define MFMA1(A, B, C) __builtin_amdgcn_mfma_f32_16x16x32_bf16(A, B, C, 0, 0, 0)

// ---------------- kernel 1: style modulation s[b][i] ----------------
__global__ __launch_bounds__(256) void style_mod_kernel(
    const float* __restrict__ style, const float* __restrict__ mod_w,
    const float* __restrict__ mod_b, float* __restrict__ s_out)
{
    int pair = blockIdx.x * 4 + (threadIdx.x >> 6);
    int lane = threadIdx.x & 63;
    int b = pair >> 9;
    int i = pair & 511;
    const float4* sv = (const float4*)(style + b * 512);
    const float4* wv = (const float4*)(mod_w + i * 512);
    float4 a0 = sv[lane * 2], a1 = sv[lane * 2 + 1];
    float4 w0 = wv[lane * 2], w1 = wv[lane * 2 + 1];
    float sum = a0.x*w0.x + a0.y*w0.y + a0.z*w0.z + a0.w*w0.w
              + a1.x*w1.x + a1.y*w1.y + a1.z*w1.z + a1.w*w1.w;
    #pragma unroll
    for (int off = 32; off; off >>= 1) sum += __shfl_xor(sum, off);
    if (lane == 0) s_out[pair] = sum + mod_b[i];
}

// ------------- kernel 2: demod + bf16 wmod, block per oc -------------
__global__ __launch_bounds__(256) void wmod_kernel(
    const float* __restrict__ weight,   // [512][4608] (e = ic*9+tap)
    const float* __restrict__ s_in,     // [16][512]
    __hip_bfloat16* __restrict__ wmod)  // [16*512][4608] (e' = tap*512+ic)
{
    int oc = blockIdx.x;
    __shared__ float w_sh[4608];
    __shared__ float s_sh[8192];
    __shared__ float q_sh[512];
    __shared__ float demod_sh[16];
    int t = threadIdx.x;
    const float* wrow = weight + (size_t)oc * KTOT;
    for (int e = t; e < 4608; e += 256) w_sh[e] = wrow[e];
    for (int e = t; e < 8192; e += 256) s_sh[e] = s_in[e];
    __syncthreads();
    for (int ic = t; ic < 512; ic += 256) {
        float q = 0.f;
        #pragma unroll
        for (int tap = 0; tap < 9; ++tap) { float w = w_sh[ic * 9 + tap]; q += w * w; }
        q_sh[ic] = q;
    }
    __syncthreads();
    int bb = t >> 4, li = t & 15;
    float part = 0.f;
    for (int ic = li; ic < 512; ic += 16) {
        float sv = s_sh[bb * 512 + ic];
        part += q_sh[ic] * sv * sv;
    }
    #pragma unroll
    for (int off = 8; off; off >>= 1) part += __shfl_xor(part, off, 16);
    if (li == 0) demod_sh[bb] = rsqrtf(part + 1e-8f);
    __syncthreads();
    for (int b2 = 0; b2 < 16; ++b2) {
        float dm = demod_sh[b2];
        const float* srow = s_sh + b2 * 512;
        __hip_bfloat16* dst = wmod + ((size_t)b2 * 512 + oc) * KTOT;
        for (int ep = t; ep < 4608; ep += 256) {
            int tap = ep >> 9, ic = ep & 511;
            dst[ep] = __float2bfloat16(w_sh[ic * 9 + tap] * srow[ic] * dm);
        }
    }
}

// ------------- kernel 3a: zero pad row of xT -------------
__global__ void zero_row_kernel(__hip_bfloat16* xT) {
    ((unsigned*)(xT + ((size_t)blockIdx.x * 4097 + 4096) * 512))[threadIdx.x] = 0u;
}

// ------------- kernel 3b: x [b][ic][pix] f32 -> xT [b][pix][ic] bf16 -------------
__global__ __launch_bounds__(256) void xpose_kernel(
    const float* __restrict__ x, __hip_bfloat16* __restrict__ xT)
{
    __shared__ __align__(16) float tile[64][68];
    int b = blockIdx.z, ic0 = blockIdx.y * 64, p0 = blockIdx.x * 64;
    int t = threadIdx.x;
    const float* xb = x + ((size_t)b * 512 + ic0) * 4096 + p0;
    int rr = t >> 4, cc = (t & 15) * 4;
    #pragma unroll
    for (int i = 0; i < 4; ++i) {
        float4 v = *(const float4*)(xb + (size_t)(rr + i * 16) * 4096 + cc);
        *(float4*)&tile[rr + i * 16][cc] = v;
    }
    __syncthreads();
    int pr = t >> 2, io = (t & 3) * 16;
    __hip_bfloat16 obuf[16];
    #pragma unroll
    for (int j = 0; j < 16; ++j) obuf[j] = __float2bfloat16(tile[io + j][pr]);
    __hip_bfloat16* dst = xT + ((size_t)b * 4097 + p0 + pr) * 512 + ic0 + io;
    *(uint4*)dst       = *(uint4*)&obuf[0];
    *(uint4*)(dst + 8) = *(uint4*)&obuf[8];
}

// ------------- kernel 4: conv, 256x256 BK=64 dbuf-2, m201 8-phase -------------
__global__ __launch_bounds__(512, 2) void conv_kernel(
    const __hip_bfloat16* __restrict__ xT,    // [16][4097][512]
    const __hip_bfloat16* __restrict__ wmod,  // [16*512][4608]
    const float* __restrict__ bias,
    float* __restrict__ out)                  // [16][512][4096]
{
    __shared__ __align__(16) __hip_bfloat16 Ash[2][256 * 64];   // 64 KB
    __shared__ __align__(16) __hip_bfloat16 Bsh[2][256 * 64];   // 64 KB
    __hip_bfloat16* const As0 = &Ash[0][0];
    __hip_bfloat16* const As1 = &Ash[1][0];
    __hip_bfloat16* const Bs0 = &Bsh[0][0];
    __hip_bfloat16* const Bs1 = &Bsh[1][0];

    const int t    = threadIdx.x;
    const int lane = t & 63;
    const int wid  = t >> 6;      // 0..7
    const int wm   = wid >> 2;    // 0..1 (M half: 128 oc rows)
    const int wn   = wid & 3;     // 0..3 (N quarter: 64 px)
    const int lr   = lane & 15;
    const int lq   = lane >> 4;

    // block decode: 512 blocks; per XCD 2 b's; oc-tile inner (B panel L2 reuse)
    int bid = blockIdx.x;
    int xcd = bid & 7, idx = bid >> 3;
    int oc1 = idx & 1;
    int nt  = (idx >> 1) & 15;
    int bb  = (idx >> 5) & 1;
    int b   = xcd * 2 + bb;
    int oc0 = oc1 * 256, n0 = nt * 256;

    const __hip_bfloat16* wb = wmod + (size_t)(b * 512 + oc0) * KTOT;
    const __hip_bfloat16* xb = xT + (size_t)b * 4097 * 512;

    // stage geometry (verified in R10/R12): unit u: row u>>3, phys col8 u&7;
    // swizzle: logical col8 = (u&7) ^ (row&7); thread t owns units t+512j.
    const int qoff = (((t & 7) ^ ((t >> 3) & 7)) * 8);
    const int srow = t >> 3;                  // 0..63
    const int p0g  = n0 + srow;
    const int y0p  = p0g >> 6, x0p = p0g & 63;

    const __hip_bfloat16* pA0 = wb + (size_t)srow * KTOT + qoff;
    const __hip_bfloat16* pA1 = pA0 + (size_t)64  * KTOT;
    const __hip_bfloat16* pA2 = pA0 + (size_t)128 * KTOT;
    const __hip_bfloat16* pA3 = pA0 + (size_t)192 * KTOT;

    // fragment-read bases (verified in R10/R12)
    const int aoff0 = (wm * 128 + lr) * 64 + ((lq       ^ (lr & 7)) * 8);
    const int aoff1 = (wm * 128 + lr) * 64 + (((4 + lq) ^ (lr & 7)) * 8);
    const int boff0 = (wn * 64  + lr) * 64 + ((lq       ^ (lr & 7)) * 8);
    const int boff1 = (wn * 64  + lr) * 64 + (((4 + lq) ^ (lr & 7)) * 8);

    f32x4 acc[8][4] = {};                 // 128 AGPR

    // per-tap B stage pointers, px rows srow+{0,64,128,192}
    const __hip_bfloat16 *pB0, *pB1, *pB2, *pB3, *nB0, *nB1, *nB2, *nB3;
    auto bptrs = [&](int tap, const __hip_bfloat16*& P0, const __hip_bfloat16*& P1,
                     const __hip_bfloat16*& P2, const __hip_bfloat16*& P3) {
        int dy = tap / 3 - 1, dx = tap % 3 - 1;
        int sx = x0p + dx;
        bool okx = ((unsigned)sx < 64u);
        int sy0 = y0p + dy;
        int q0 = (okx & ((unsigned)(sy0    ) < 64u)) ? ((sy0    ) * 64 + sx) : 4096;
        int q1 = (okx & ((unsigned)(sy0 + 1) < 64u)) ? ((sy0 + 1) * 64 + sx) : 4096;
        int q2 = (okx & ((unsigned)(sy0 + 2) < 64u)) ? ((sy0 + 2) * 64 + sx) : 4096;
        int q3 = (okx & ((unsigned)(sy0 + 3) < 64u)) ? ((sy0 + 3) * 64 + sx) : 4096;
        P0 = xb + (size_t)q0 * 512 + qoff;
        P1 = xb + (size_t)q1 * 512 + qoff;
        P2 = xb + (size_t)q2 * 512 + qoff;
        P3 = xb + (size_t)q3 * 512 + qoff;
    };

// frag reads: 4 b128 each (a-quad or b-quad); +4096 elems = mi 4..7 rows
#define PRA(DST, BUF, OFFB) { _Pragma("unroll") \
    for (int mi = 0; mi < 4; ++mi) DST[mi] = *(const bf16x8*)(&(BUF)[(OFFB) + mi * 1024]); }
#define PRB(DST, BUF, OFFB) { _Pragma("unroll") \
    for (int ni = 0; ni < 4; ++ni) DST[ni] = *(const bf16x8*)(&(BUF)[(OFFB) + ni * 1024]); }

#define MFQ(M0, AV, BV) { \
    __builtin_amdgcn_s_setprio(1); \
    _Pragma("unroll") for (int mi = 0; mi < 4; ++mi) \
        _Pragma("unroll") for (int ni = 0; ni < 4; ++ni) \
            acc[(M0) + mi][ni] = MFMA1(AV[mi], BV[ni], acc[(M0) + mi][ni]); \
    __builtin_amdgcn_s_setprio(0); }

#define GA_ALL(DST, OFF) { \
    GLL16(pA0 + (OFF), &(DST)[t * 8]);            GLL16(pA1 + (OFF), &(DST)[(t + 512) * 8]); \
    GLL16(pA2 + (OFF), &(DST)[(t + 1024) * 8]);   GLL16(pA3 + (OFF), &(DST)[(t + 1536) * 8]); }
#define GA_H0(DST, OFF) { \
    GLL16(pA0 + (OFF), &(DST)[t * 8]);            GLL16(pA1 + (OFF), &(DST)[(t + 512) * 8]); }
#define GA_H1(DST, OFF) { \
    GLL16(pA2 + (OFF), &(DST)[(t + 1024) * 8]);   GLL16(pA3 + (OFF), &(DST)[(t + 1536) * 8]); }
#define GB_H0(DST, P0, P1, OFF) { \
    GLL16((P0) + (OFF), &(DST)[t * 8]);           GLL16((P1) + (OFF), &(DST)[(t + 512) * 8]); }
#define GB_H1(DST, P2, P3, OFF) { \
    GLL16((P2) + (OFF), &(DST)[(t + 1024) * 8]);  GLL16((P3) + (OFF), &(DST)[(t + 1536) * 8]); }

// Iter C (0..3 within tap): computes tiles 2C (buf0), 2C+1 (buf1).
// Stages: ph1 A(2C+1)->buf1; ph4 Bh0(buf0,2C+2); ph5 Bh1+Ah0(buf0);
// ph6 Ah1(buf0); ph8 B(2C+3)->buf1. C==3 targets cross into next tap (nB).
#define ITER(C, TAIL) { \
    bf16x8 av[4], bv[4]; \
    /* ph1 */ \
    PRA(av, As0, aoff0); PRB(bv, Bs0, boff0); \
    GA_ALL(As1, ((C) * 2 + 1) * 64); \
    BAR(); LGKM0(); MFQ(0, av, bv); BAR(); \
    /* ph2 */ \
    PRA(av, As0, aoff0 + 4096); \
    BAR(); LGKM0(); MFQ(4, av, bv); BAR(); \
    /* ph3 */ \
    PRA(av, As0, aoff1); PRB(bv, Bs0, boff1); \
    BAR(); LGKM0(); MFQ(0, av, bv); BAR(); \
    /* ph4 */ \
    PRA(av, As0, aoff1 + 4096); \
    if (!(TAIL)) { \
        if ((C) < 3) { GB_H0(Bs0, pB0, pB1, ((C) * 2 + 2) * 64); } \
        else         { GB_H0(Bs0, nB0, nB1, 0); } } \
    BAR(); LGKM0(); MFQ(4, av, bv); \
    if (TAIL) { vmw<0>(); } else { vmw<2>(); } \
    BAR(); \
    /* ph5 */ \
    PRA(av, As1, aoff0); PRB(bv, Bs1, boff0); \
    if (!(TAIL)) { \
        if ((C) < 3) { GB_H1(Bs0, pB2, pB3, ((C) * 2 + 2) * 64); } \
        else         { GB_H1(Bs0, nB2, nB3, 0); } \
        GA_H0(As0, ((C) * 2 + 2) * 64); } \
    BAR(); LGKM0(); MFQ(0, av, bv); BAR(); \
    /* ph6 */ \
    PRA(av, As1, aoff0 + 4096); \
    if (!(TAIL)) { GA_H1(As0, ((C) * 2 + 2) * 64); } \
    BAR(); LGKM0(); MFQ(4, av, bv); BAR(); \
    /* ph7 */ \
    PRA(av, As1, aoff1); PRB(bv, Bs1, boff1); \
    BAR(); LGKM0(); MFQ(0, av, bv); BAR(); \
    /* ph8 */ \
    PRA(av, As1, aoff1 + 4096); \
    if (!(TAIL)) { \
        if ((C) < 3) { GB_H0(Bs1, pB0, pB1, ((C) * 2 + 3) * 64); GB_H1(Bs1, pB2, pB3, ((C) * 2 + 3) * 64); } \
        else         { GB_H0(Bs1, nB0, nB1, 64); GB_H1(Bs1, nB2, nB3, 64); } } \
    BAR(); LGKM0(); MFQ(4, av, bv); \
    if (!(TAIL)) { vmw<4>(); } \
    BAR(); }

    // ---- prologue: tile0 A+B -> buf0; tile1 B -> buf1; vmw(4) -> tile0 resident ----
    bptrs(0, pB0, pB1, pB2, pB3);
    GA_ALL(As0, 0);
    GB_H0(Bs0, pB0, pB1, 0);  GB_H1(Bs0, pB2, pB3, 0);
    GB_H0(Bs1, pB0, pB1, 64); GB_H1(Bs1, pB2, pB3, 64);
    vmw<4>();
    BAR();

    // ---- taps 0..7: 4 full iters each ----
    for (int tap = 0; tap < 8; ++tap) {
        bptrs(tap + 1, nB0, nB1, nB2, nB3);
        ITER(0, false); ITER(1, false); ITER(2, false); ITER(3, false);
        pA0 += 512; pA1 += 512; pA2 += 512; pA3 += 512;
        pB0 = nB0; pB1 = nB1; pB2 = nB2; pB3 = nB3;
    }
    // ---- tap 8: 3 full iters + tail ----
    ITER(0, false); ITER(1, false); ITER(2, false);
    ITER(3, true);
#undef ITER
#undef PRA
#undef PRB
#undef MFQ
#undef GA_ALL
#undef GA_H0
#undef GA_H1
#undef GB_H0
#undef GB_H1

    // ---- epilogue ----
    #pragma unroll
    for (int mi = 0; mi < 8; ++mi) {
        int oc = oc0 + wm * 128 + mi * 16 + lq * 4;
        #pragma unroll
        for (int ni = 0; ni < 4; ++ni) {
            int n = n0 + wn * 64 + ni * 16 + lr;
            #pragma unroll
            for (int v = 0; v < 4; ++v) {
                float r = acc[mi][ni][v] + bias[oc + v];
                out[((size_t)(b * OC + oc + v)) * HW + n] = r;
            }
        }
    }
}

extern "C" void kernel_launch(void* const* d_in, const int* in_sizes, int n_in,
                              void* d_out, int out_size, void* d_ws, size_t ws_size,
                              hipStream_t stream) {
    const float* x      = (const float*)d_in[0];
    const float* style  = (const float*)d_in[1];
    const float* weight = (const float*)d_in[2];
    const float* bias   = (const float*)d_in[3];
    const float* mod_w  = (const float*)d_in[4];
    const float* mod_b  = (const float*)d_in[5];
    float* out = (float*)d_out;

    // ws: s [32KB] | wmod bf16 [75.5MB] | xT bf16 [67.2MB]
    float* s_ws = (float*)d_ws;
    __hip_bfloat16* wmod = (__hip_bfloat16*)((char*)d_ws + 32768);
    __hip_bfloat16* xT   = (__hip_bfloat16*)((char*)d_ws + 32768 + (size_t)16 * 512 * KTOT * 2);

    style_mod_kernel<<<2048, 256, 0, stream>>>(style, mod_w, mod_b, s_ws);
    wmod_kernel<<<512, 256, 0, stream>>>(weight, s_ws, wmod);
    zero_row_kernel<<<16, 256, 0, stream>>>(xT);
    dim3 tgrid(64, 8, 16);
    xpose_kernel<<<tgrid, 256, 0, stream>>>(x, xT);
    conv_kernel<<<512, 512, 0, stream>>>(xT, wmod, bias, out);
}